// Round 9
// baseline (187.990 us; speedup 1.0000x reference)
//
#include <hip/hip_runtime.h>
#include <math.h>

// ---------------------------------------------------------------------------
// Deep4Net via bf16 MFMA 32x32x16 (fp32 accum), 3 dispatches:
//  k_prep2  : fuse conv1+conv2 weights, transpose+pad all weights to bf16
//  k_cmfma  : conv12 -> p1T[b][330][32] bf16 global (2816 blocks)
//  k_mega   : per-sample block: conv3 -> conv4 -> conv5 -> routed head,
//             all intermediates in LDS. Overlapping n-tiles (stride 30, width
//             32) keep every pool-of-3 inside one tile -> in-register shuffle
//             pooling (no LDS scratch, 4 barriers total).
// C/D layout (32x32): col = lane&31, row = (reg&3)+8*(reg>>2)+4*(lane>>5).
//
// Workspace: float region then short(bf16) region.
#define F_BC   0         // 32   combined bias (padded)
#define F_B2   32        // 64
#define F_B3   96        // 128
#define F_B4   224       // 224
#define SHORT_BASE 717696
#define WK12   0         // [10][32][32]
#define WK3    10240     // [10][64][32]
#define WK4    30720     // [10][128][64]
#define WK5    112640    // [10][224][128]
#define P1T    399360    // [256][330][32]
// ---------------------------------------------------------------------------

typedef __attribute__((ext_vector_type(8))) short short8;
typedef __attribute__((ext_vector_type(16))) float f32x16;

__device__ __forceinline__ short f2bf(float f) {
    union { float f; unsigned u; } v; v.f = f;
    unsigned r = v.u + 0x7FFF + ((v.u >> 16) & 1);
    return (short)(r >> 16);
}

// ---- K0: weight prep ------------------------------------------------------
__global__ __launch_bounds__(256) void k_prep2(
    const float* __restrict__ wt, const float* __restrict__ bt,
    const float* __restrict__ wsp, const float* __restrict__ bsp,
    const float* __restrict__ w2, const float* __restrict__ b2,
    const float* __restrict__ w3, const float* __restrict__ b3,
    const float* __restrict__ w4, const float* __restrict__ b4,
    float* __restrict__ wsf, short* __restrict__ wss) {
    int idx = blockIdx.x * 256 + threadIdx.x;
    if (idx < 448) {                           // padded biases (f32)
        float v = 0.f;
        if (idx < 32) {
            int o = idx;
            if (o < 25) {
                v = bsp[o];
                for (int i = 0; i < 25; ++i) {
                    float rs = 0.f;
                    for (int c = 0; c < 22; ++c) rs += wsp[(o * 25 + i) * 22 + c];
                    v += bt[i] * rs;
                }
            }
        } else if (idx < 96)  { int o = idx - 32;  v = (o < 50)  ? b2[o] : 0.f; }
        else if (idx < 224)   { int o = idx - 96;  v = (o < 100) ? b3[o] : 0.f; }
        else                  { int o = idx - 224; v = (o < 200) ? b4[o] : 0.f; }
        wsf[idx] = v;
        return;
    }
    int j = idx - 448;
    if (j < 10240) {                           // wk12 [k][32][32] (combined)
        int k = j / 1024, o = (j / 32) % 32, i = j % 32;
        float v = 0.f;
        if (o < 25 && i < 22)
            for (int q = 0; q < 25; ++q) v += wt[q * 10 + k] * wsp[(o * 25 + q) * 22 + i];
        wss[WK12 + j] = f2bf(v);
        return;
    }
    j -= 10240;
    if (j < 20480) {                           // wk3 [k][64][32]
        int k = j / 2048, o = (j / 32) % 64, i = j % 32;
        float v = (o < 50 && i < 25) ? w2[(o * 25 + i) * 10 + k] : 0.f;
        wss[WK3 + j] = f2bf(v);
        return;
    }
    j -= 20480;
    if (j < 81920) {                           // wk4 [k][128][64]
        int k = j / 8192, o = (j / 64) % 128, i = j % 64;
        float v = (o < 100 && i < 50) ? w3[(o * 50 + i) * 10 + k] : 0.f;
        wss[WK4 + j] = f2bf(v);
        return;
    }
    j -= 81920;
    if (j < 286720) {                          // wk5 [k][224][128]
        int k = j / 28672, o = (j / 128) % 224, i = j % 128;
        float v = (o < 200 && i < 100) ? w4[(o * 100 + i) * 10 + k] : 0.f;
        wss[WK5 + j] = f2bf(v);
    }
}

// ---- K1: conv12 via 32x32x16 MFMA -> p1T[b][330][32] bf16 -----------------
__global__ __launch_bounds__(192) void k_conv12m(
    const short* __restrict__ wk, const float* __restrict__ bias,
    const float* __restrict__ xf32, short* __restrict__ outT) {
    constexpr int NCHUNK = 96, ROWS = NCHUNK + 9, XSTR = 36, SSTR = 33;
    __shared__ short xs[ROWS * XSTR];
    __shared__ float sc[NCHUNK * SSTR];

    int idx = blockIdx.x;
    int b = idx % 256;
    int nc = idx / 256;            // 0..10
    int t0 = nc * NCHUNK;
    int tid = threadIdx.x;

    const float* xb = xf32 + b * 22000;
    for (int i = tid; i < 32 * ROWS; i += 192) {
        int c = i / ROWS, r = i - c * ROWS;
        short v = 0;
        if (c < 22) {
            int t = t0 + r; if (t > 999) t = 999;
            v = f2bf(xb[c * 1000 + t]);
        }
        xs[r * XSTR + c] = v;
    }
    __syncthreads();

    int w = tid >> 6, lane = tid & 63, l31 = lane & 31, half = lane >> 5;
    int nt = w;                    // 3 n-tiles of 32

    f32x16 acc = {};
    const short* wbase = wk + (size_t)l31 * 32 + half * 8;
#pragma unroll 2
    for (int k = 0; k < 10; ++k) {
#pragma unroll
        for (int kb = 0; kb < 2; ++kb) {
            short8 a = *(const short8*)(wbase + (size_t)k * 32 * 32 + kb * 16);
            short8 bf = *(const short8*)(xs + (nt * 32 + l31 + k) * XSTR +
                                         kb * 16 + half * 8);
            acc = __builtin_amdgcn_mfma_f32_32x32x16_bf16(a, bf, acc, 0, 0, 0);
        }
    }
    {
        float* scl = sc + (nt * 32 + l31) * SSTR + 4 * half;
#pragma unroll
        for (int reg = 0; reg < 16; ++reg)
            scl[(reg & 3) + 8 * (reg >> 2)] = acc[reg];
    }
    __syncthreads();

    int pc0 = nc * 32;
    for (int i = tid; i < 32 * 32; i += 192) {
        int tp = i >> 5, ol = i & 31;
        if (pc0 + tp < 330) {
            float s0 = sc[(tp * 3 + 0) * SSTR + ol];
            float s1 = sc[(tp * 3 + 1) * SSTR + ol];
            float s2 = sc[(tp * 3 + 2) * SSTR + ol];
            float m = fmaxf(fmaxf(s0, s1), s2) + bias[ol];
            float e = m > 0.f ? m : __expf(m) - 1.f;
            outT[(size_t)b * 330 * 32 + (size_t)(pc0 + tp) * 32 + ol] = f2bf(e);
        }
    }
}

// ---- K2: mega — conv3/conv4/conv5/head per sample -------------------------
__global__ __launch_bounds__(512) void k_mega(
    const short* __restrict__ p1g, const float* __restrict__ wsf,
    const short* __restrict__ wk3, const short* __restrict__ wk4,
    const short* __restrict__ wk5,
    const float* __restrict__ hW, const float* __restrict__ hB,
    const int* __restrict__ sid, float* __restrict__ out) {
    __shared__ __align__(16) short p1s[341 * 36];   // 24552 B; later p3s+feats
    __shared__ __align__(16) short p2s[131 * 68];   // 17816 B
    __shared__ float biasS[448];
    short* p3s = p1s;                               // [41][132] shorts
    float* feats = (float*)((char*)p1s + 10832);    // 1400 f32

    int b = blockIdx.x, tid = threadIdx.x;

    // ---- stage p1 tile; zero p2s garbage rows; preload biases ----
    {
        const short8* src = (const short8*)(p1g + (size_t)b * 330 * 32);
        for (int i = tid; i < 341 * 4; i += 512) {
            int r = i >> 2, v = i & 3;
            short8 val = {};
            if (r < 330) val = src[r * 4 + v];
            *(short8*)(p1s + r * 36 + v * 8) = val;
        }
        for (int i = tid; i < 24 * 68; i += 512) p2s[107 * 68 + i] = 0;
        for (int i = tid; i < 448; i += 512) biasS[i] = wsf[i];
    }
    __syncthreads();

    int w = tid >> 6, lane = tid & 63, l31 = lane & 31, half = lane >> 5;

    // ---- conv3: p1s -> p2s[107][68]; tasks = mt(2) x nt(11) ----
    for (int task = w; task < 22; task += 8) {
        int mt = task / 11, nt = task % 11;
        f32x16 acc = {};
        const short* wbase = wk3 + (size_t)(mt * 32 + l31) * 32 + half * 8;
#pragma unroll 2
        for (int k = 0; k < 10; ++k) {
            const short* wp = wbase + (size_t)k * 64 * 32;
            const short* xr = p1s + (nt * 30 + l31 + k) * 36 + half * 8;
#pragma unroll
            for (int kb = 0; kb < 2; ++kb)
                acc = __builtin_amdgcn_mfma_f32_32x32x16_bf16(
                    *(const short8*)(wp + kb * 16), *(const short8*)(xr + kb * 16),
                    acc, 0, 0, 0);
        }
        bool actL = (l31 % 3 == 0) && (l31 < 30);
        int tp = nt * 10 + l31 / 3;
#pragma unroll
        for (int reg = 0; reg < 16; ++reg) {
            float v = acc[reg];
            float v1 = __shfl_down(v, 1);
            float v2 = __shfl_down(v, 2);
            if (actL && tp < 107) {
                int ol = mt * 32 + (reg & 3) + 8 * (reg >> 2) + 4 * half;
                float m = fmaxf(fmaxf(v, v1), v2) + biasS[32 + ol];
                float e = m > 0.f ? m : __expf(m) - 1.f;
                p2s[tp * 68 + ol] = f2bf(e);
            }
        }
    }
    __syncthreads();

    // ---- conv4: p2s -> p3s[32][132]; tasks = mt(4) x nt(4) ----
    for (int task = w; task < 16; task += 8) {
        int mt = task >> 2, nt = task & 3;
        f32x16 acc = {};
        const short* wbase = wk4 + (size_t)(mt * 32 + l31) * 64 + half * 8;
#pragma unroll 2
        for (int k = 0; k < 10; ++k) {
            const short* wp = wbase + (size_t)k * 128 * 64;
            const short* xr = p2s + (nt * 30 + l31 + k) * 68 + half * 8;
#pragma unroll
            for (int kb = 0; kb < 4; ++kb)
                acc = __builtin_amdgcn_mfma_f32_32x32x16_bf16(
                    *(const short8*)(wp + kb * 16), *(const short8*)(xr + kb * 16),
                    acc, 0, 0, 0);
        }
        bool actL = (l31 % 3 == 0) && (l31 < 30);
        int tp = nt * 10 + l31 / 3;
#pragma unroll
        for (int reg = 0; reg < 16; ++reg) {
            float v = acc[reg];
            float v1 = __shfl_down(v, 1);
            float v2 = __shfl_down(v, 2);
            if (actL && tp < 32) {
                int ol = mt * 32 + (reg & 3) + 8 * (reg >> 2) + 4 * half;
                float m = fmaxf(fmaxf(v, v1), v2) + biasS[96 + ol];
                float e = m > 0.f ? m : __expf(m) - 1.f;
                p3s[tp * 132 + ol] = f2bf(e);
            }
        }
    }
    __syncthreads();

    // ---- conv5: p3s -> feats[1400]; tasks = mt(7) ----
    for (int task = w; task < 7; task += 8) {
        int mt = task;
        f32x16 acc = {};
        const short* wbase = wk5 + (size_t)(mt * 32 + l31) * 128 + half * 8;
#pragma unroll 2
        for (int k = 0; k < 10; ++k) {
            const short* wp = wbase + (size_t)k * 224 * 128;
            const short* xr = p3s + (l31 + k) * 132 + half * 8;
#pragma unroll
            for (int kb = 0; kb < 8; ++kb)
                acc = __builtin_amdgcn_mfma_f32_32x32x16_bf16(
                    *(const short8*)(wp + kb * 16), *(const short8*)(xr + kb * 16),
                    acc, 0, 0, 0);
        }
        bool actL = (l31 % 3 == 0) && (l31 < 21);
        int tp = l31 / 3;
#pragma unroll
        for (int reg = 0; reg < 16; ++reg) {
            float v = acc[reg];
            float v1 = __shfl_down(v, 1);
            float v2 = __shfl_down(v, 2);
            int og = mt * 32 + (reg & 3) + 8 * (reg >> 2) + 4 * half;
            if (actL && og < 200) {
                float m = fmaxf(fmaxf(v, v1), v2) + biasS[224 + og];
                feats[og * 7 + tp] = m > 0.f ? m : __expf(m) - 1.f;
            }
        }
    }
    __syncthreads();

    // ---- routed head: 4 waves, one output each ----
    if (w < 4) {
        int sidb = sid[b];
        const float* wrow = hW + (size_t)(sidb * 4 + w) * 1400;
        float a = 0.f;
        for (int f = lane; f < 1400; f += 64) a += wrow[f] * feats[f];
#pragma unroll
        for (int off = 32; off; off >>= 1) a += __shfl_down(a, off);
        if (lane == 0) out[b * 4 + w] = a + hB[sidb * 4 + w];
    }
}

extern "C" void kernel_launch(void* const* d_in, const int* in_sizes, int n_in,
                              void* d_out, int out_size, void* d_ws, size_t ws_size,
                              hipStream_t stream) {
    const float* x   = (const float*)d_in[0];
    const int*   sid = (const int*)d_in[1];
    const float* wt  = (const float*)d_in[2];
    const float* bt  = (const float*)d_in[3];
    const float* wsp = (const float*)d_in[4];
    const float* bsp = (const float*)d_in[5];
    const float* w2  = (const float*)d_in[6];
    const float* b2  = (const float*)d_in[7];
    const float* w3  = (const float*)d_in[8];
    const float* b3  = (const float*)d_in[9];
    const float* w4  = (const float*)d_in[10];
    const float* b4  = (const float*)d_in[11];
    const float* hW  = (const float*)d_in[12];
    const float* hB  = (const float*)d_in[13];
    float* out = (float*)d_out;
    float* wsf = (float*)d_ws;
    short* wss = (short*)d_ws + SHORT_BASE;

    k_prep2<<<1562, 256, 0, stream>>>(wt, bt, wsp, bsp, w2, b2, w3, b3, w4, b4,
                                      wsf, wss);
    k_conv12m<<<256 * 11, 192, 0, stream>>>(wss + WK12, wsf + F_BC, x, wss + P1T);
    k_mega<<<256, 512, 0, stream>>>(wss + P1T, wsf, wss + WK3, wss + WK4,
                                    wss + WK5, hW, hB, sid, out);
}